// Round 1
// baseline (300.349 us; speedup 1.0000x reference)
//
#include <hip/hip_runtime.h>
#include <math.h>

// SuperLoss: tau = mean(loss); y = 0.5*max(-2/e, (l-tau)/lam);
// sigma = exp(-W0(y)); out = (l-tau)*sigma + lam*W0(y)^2
//
// Pass 1: block partial sums (2048 partials in d_ws)
// Pass 2: finalize tau (double accumulate) -> d_ws[2048]
// Pass 3: elementwise, float4-vectorized, 4 Halley iterations for W0

#define NPART 2048
#define NEG_2_OVER_E (-0.7357588823428847f)

__device__ __forceinline__ float fast_rcp(float x) {
    return __builtin_amdgcn_rcpf(x);
}

__device__ __forceinline__ float lambertw0_f(float y) {
    // Series init near branch point (y<0), log(1+y) init otherwise.
    float ey1 = fmaf(2.718281828459045f, y, 1.0f);
    float p = sqrtf(fmaxf(2.0f * ey1, 0.0f));
    // -1 + p - p^2/3 + (11/72) p^3, Horner
    float w_branch = fmaf(p, fmaf(p, fmaf(p, 11.0f / 72.0f, -1.0f / 3.0f), 1.0f), -1.0f);
    float w_log = __logf(1.0f + y);  // y >= 0 here, no cancellation
    float w = (y < 0.0f) ? w_branch : w_log;
    // Halley iterations (cubic convergence; 4 is overkill vs ref's 8-to-converge)
#pragma unroll
    for (int i = 0; i < 4; ++i) {
        float ew = __expf(w);
        float f = fmaf(w, ew, -y);
        float wp1 = w + 1.0f;
        float safe = (fabsf(wp1) < 1e-6f) ? 1e-6f : wp1;
        float denom = ew * wp1 - (w + 2.0f) * f * 0.5f * fast_rcp(safe);
        denom = (fabsf(denom) < 1e-12f) ? 1e-12f : denom;
        w = w - f * fast_rcp(denom);
    }
    return w;
}

__device__ __forceinline__ float superloss_elem(float l, float tau) {
    float d = l - tau;
    float y = 0.5f * fmaxf(NEG_2_OVER_E, d * 10.0f);
    float w = lambertw0_f(y);
    float sigma = __expf(-w);
    return fmaf(d, sigma, 0.1f * w * w);
}

__global__ void reduce_partial(const float4* __restrict__ x, float* __restrict__ partials,
                               int n4, const float* __restrict__ x_scalar, int n) {
    float s = 0.0f;
    int stride = gridDim.x * blockDim.x;
    for (int i = blockIdx.x * blockDim.x + threadIdx.x; i < n4; i += stride) {
        float4 v = x[i];
        s += (v.x + v.y) + (v.z + v.w);
    }
    // tail elements (none for n = 2^25, but be safe)
    if (blockIdx.x == 0 && threadIdx.x == 0) {
        for (int i = 4 * n4; i < n; ++i) s += x_scalar[i];
    }
    // wave64 shuffle reduce
#pragma unroll
    for (int off = 32; off > 0; off >>= 1) s += __shfl_down(s, off, 64);
    __shared__ float smem[4];
    int lane = threadIdx.x & 63;
    int wave = threadIdx.x >> 6;
    if (lane == 0) smem[wave] = s;
    __syncthreads();
    if (threadIdx.x == 0) {
        partials[blockIdx.x] = (smem[0] + smem[1]) + (smem[2] + smem[3]);
    }
}

__global__ void finalize_tau(const float* __restrict__ partials, float* __restrict__ tau_p, int n) {
    double s = 0.0;
    for (int i = threadIdx.x; i < NPART; i += 256) s += (double)partials[i];
#pragma unroll
    for (int off = 32; off > 0; off >>= 1) s += __shfl_down(s, off, 64);
    __shared__ double smem[4];
    int lane = threadIdx.x & 63;
    int wave = threadIdx.x >> 6;
    if (lane == 0) smem[wave] = s;
    __syncthreads();
    if (threadIdx.x == 0) {
        double total = (smem[0] + smem[1]) + (smem[2] + smem[3]);
        tau_p[0] = (float)(total / (double)n);
    }
}

__global__ void superloss_main(const float4* __restrict__ x, float4* __restrict__ out,
                               const float* __restrict__ tau_p, int n4) {
    int i = blockIdx.x * blockDim.x + threadIdx.x;
    if (i >= n4) return;
    float tau = *tau_p;
    float4 v = x[i];
    float4 r;
    r.x = superloss_elem(v.x, tau);
    r.y = superloss_elem(v.y, tau);
    r.z = superloss_elem(v.z, tau);
    r.w = superloss_elem(v.w, tau);
    out[i] = r;
}

__global__ void superloss_tail(const float* __restrict__ x, float* __restrict__ out,
                               const float* __restrict__ tau_p, int start, int n) {
    int i = start + blockIdx.x * blockDim.x + threadIdx.x;
    if (i < n) out[i] = superloss_elem(x[i], *tau_p);
}

extern "C" void kernel_launch(void* const* d_in, const int* in_sizes, int n_in,
                              void* d_out, int out_size, void* d_ws, size_t ws_size,
                              hipStream_t stream) {
    const float* loss = (const float*)d_in[0];
    float* out = (float*)d_out;
    int n = in_sizes[0];
    int n4 = n / 4;
    float* ws = (float*)d_ws;          // ws[0..NPART-1] partials, ws[NPART] = tau
    float* tau_p = ws + NPART;

    reduce_partial<<<NPART, 256, 0, stream>>>((const float4*)loss, ws, n4, loss, n);
    finalize_tau<<<1, 256, 0, stream>>>(ws, tau_p, n);

    int blocks = (n4 + 255) / 256;
    superloss_main<<<blocks, 256, 0, stream>>>((const float4*)loss, (float4*)out, tau_p, n4);

    int tail = n - 4 * n4;
    if (tail > 0) {
        superloss_tail<<<(tail + 255) / 256, 256, 0, stream>>>(loss, out, tau_p, 4 * n4, n);
    }
}

// Round 2
// 263.090 us; speedup vs baseline: 1.1416x; 1.1416x over previous
//
#include <hip/hip_runtime.h>
#include <math.h>

// SuperLoss: tau = mean(loss); y = 0.5*max(-2/e, (l-tau)/lam) = max(-1/e, 5d);
// w = W0(y); out_unclamped = d*e^{-w} + 0.1 w^2 = 0.1*w*(w+2)  [since w e^w = y = 5d]
// out_clamped (5d < -1/e): w=-1, sigma=e -> out = e*d + 0.1  (exact closed form)
//
// Pass 1: block partial sums (2048 partials in d_ws)
// Pass 2: finalize tau (double accumulate) -> d_ws[2048]
// Pass 3: elementwise, float4-vectorized, 2 Halley iterations for W0
//         (init err <= 0.29, cubic convergence -> ~1e-8; threshold 2.5e-2)

#define NPART 2048
#define E_F 2.7182818f            // rounds to fp32-nearest of e
#define NEG_INV_E (-0.36787942f)  // 0.5 * fp32(-2/e); exact halving

__device__ __forceinline__ float fast_rcp(float x) {
    return __builtin_amdgcn_rcpf(x);
}

__device__ __forceinline__ float lambertw0_f(float y) {
    // y in [-1/e, ~3]. Series init near branch point (y<0), log(1+y) otherwise.
    float ey1 = fmaf(E_F, y, 1.0f);
    float p2 = fmaxf(ey1 + ey1, 0.0f);
    float p = sqrtf(p2);
    // -1 + p - p^2/3 + (11/72) p^3, Horner
    float w_b = fmaf(p, fmaf(p, fmaf(p, 0.15277778f, -0.33333334f), 1.0f), -1.0f);
    float w_l = __logf(1.0f + y);  // y >= 0 here, no cancellation
    float w = (y < 0.0f) ? w_b : w_l;
    // Halley, rearranged: dw = 2*f*wp1 / (2*ew*wp1^2 - (w+2)*f)
    // Denominator >= ~wp1^2 * 3/(2e) > 0 near branch; +1e-20 is the only guard
    // needed (avoids 0*inf = NaN at the exact branch point).
#pragma unroll
    for (int i = 0; i < 2; ++i) {
        float ew = __expf(w);
        float f = fmaf(w, ew, -y);
        float wp1 = w + 1.0f;
        float A = ew * wp1;
        float t = (wp1 + 1.0f) * f;               // (w+2)*f
        float denom = fmaf(A + A, wp1, -t) + 1e-20f;
        float r = fast_rcp(denom);
        float u = f * wp1;
        w = fmaf(-u, r + r, w);                    // w -= 2*f*wp1/denom
    }
    return w;
}

__device__ __forceinline__ float superloss_elem(float l, float tau) {
    float d = l - tau;
    float t5 = 5.0f * d;                 // == 0.5*(10d); exact vs ref's 0.5*max form
    float y = fmaxf(NEG_INV_E, t5);
    float w = lambertw0_f(y);
    float out_u = 0.1f * (w * (w + 2.0f));   // w/5 + 0.1 w^2
    float out_c = fmaf(E_F, d, 0.1f);        // clamped: sigma = e, w = -1 (exact)
    return (t5 < NEG_INV_E) ? out_c : out_u;
}

__global__ void reduce_partial(const float4* __restrict__ x, float* __restrict__ partials,
                               int n4, const float* __restrict__ x_scalar, int n) {
    float s = 0.0f;
    int stride = gridDim.x * blockDim.x;
    for (int i = blockIdx.x * blockDim.x + threadIdx.x; i < n4; i += stride) {
        float4 v = x[i];
        s += (v.x + v.y) + (v.z + v.w);
    }
    if (blockIdx.x == 0 && threadIdx.x == 0) {
        for (int i = 4 * n4; i < n; ++i) s += x_scalar[i];
    }
#pragma unroll
    for (int off = 32; off > 0; off >>= 1) s += __shfl_down(s, off, 64);
    __shared__ float smem[4];
    int lane = threadIdx.x & 63;
    int wave = threadIdx.x >> 6;
    if (lane == 0) smem[wave] = s;
    __syncthreads();
    if (threadIdx.x == 0) {
        partials[blockIdx.x] = (smem[0] + smem[1]) + (smem[2] + smem[3]);
    }
}

__global__ void finalize_tau(const float* __restrict__ partials, float* __restrict__ tau_p, int n) {
    double s = 0.0;
    for (int i = threadIdx.x; i < NPART; i += 256) s += (double)partials[i];
#pragma unroll
    for (int off = 32; off > 0; off >>= 1) s += __shfl_down(s, off, 64);
    __shared__ double smem[4];
    int lane = threadIdx.x & 63;
    int wave = threadIdx.x >> 6;
    if (lane == 0) smem[wave] = s;
    __syncthreads();
    if (threadIdx.x == 0) {
        double total = (smem[0] + smem[1]) + (smem[2] + smem[3]);
        tau_p[0] = (float)(total / (double)n);
    }
}

__global__ void superloss_main(const float4* __restrict__ x, float4* __restrict__ out,
                               const float* __restrict__ tau_p, int n4) {
    int i = blockIdx.x * blockDim.x + threadIdx.x;
    if (i >= n4) return;
    float tau = *tau_p;
    float4 v = x[i];
    float4 r;
    r.x = superloss_elem(v.x, tau);
    r.y = superloss_elem(v.y, tau);
    r.z = superloss_elem(v.z, tau);
    r.w = superloss_elem(v.w, tau);
    out[i] = r;
}

__global__ void superloss_tail(const float* __restrict__ x, float* __restrict__ out,
                               const float* __restrict__ tau_p, int start, int n) {
    int i = start + blockIdx.x * blockDim.x + threadIdx.x;
    if (i < n) out[i] = superloss_elem(x[i], *tau_p);
}

extern "C" void kernel_launch(void* const* d_in, const int* in_sizes, int n_in,
                              void* d_out, int out_size, void* d_ws, size_t ws_size,
                              hipStream_t stream) {
    const float* loss = (const float*)d_in[0];
    float* out = (float*)d_out;
    int n = in_sizes[0];
    int n4 = n / 4;
    float* ws = (float*)d_ws;          // ws[0..NPART-1] partials, ws[NPART] = tau
    float* tau_p = ws + NPART;

    reduce_partial<<<NPART, 256, 0, stream>>>((const float4*)loss, ws, n4, loss, n);
    finalize_tau<<<1, 256, 0, stream>>>(ws, tau_p, n);

    int blocks = (n4 + 255) / 256;
    superloss_main<<<blocks, 256, 0, stream>>>((const float4*)loss, (float4*)out, tau_p, n4);

    int tail = n - 4 * n4;
    if (tail > 0) {
        superloss_tail<<<(tail + 255) / 256, 256, 0, stream>>>(loss, out, tau_p, 4 * n4, n);
    }
}

// Round 3
// 243.066 us; speedup vs baseline: 1.2357x; 1.0824x over previous
//
#include <hip/hip_runtime.h>
#include <math.h>

// SuperLoss: tau = mean(loss); y = max(-1/e, 5d), d = l - tau;
// w = W0(y); unclamped: out = d*e^{-w} + 0.1 w^2 = 0.1*w*(w+2)  [w e^w = y = 5d]
// clamped (5d < -1/e): w = -1, sigma = e -> out = e*d + 0.1  (exact closed form)
//
// W0 via single Pade[2/2] init in branch variable p = sqrt(2(e*y+1)):
//   (w+1)/p ~= (1 + 0.5p + 0.018055p^2)/(1 + 0.833323p + 0.143051p^2)
// max init err 0.0133 over p in [0,3.95]; one Newton step -> <= 7e-5.
// No log, no branch select in the init. 4 transcendentals/elem total.
//
// Pass 1: block partial sums (2048 partials in d_ws)
// Pass 2: finalize tau (double accumulate) -> d_ws[2048]
// Pass 3: elementwise, float4-vectorized

#define NPART 2048
#define E_F 2.7182818f
#define NEG_INV_E (-0.36787942f)

__device__ __forceinline__ float fast_rcp(float x) {
    return __builtin_amdgcn_rcpf(x);
}

__device__ __forceinline__ float superloss_elem(float l, float tau) {
    float d = l - tau;
    float t5 = 5.0f * d;
    float y = fmaxf(NEG_INV_E, t5);
    // p = sqrt(2*(e*y + 1)); clamp tiny negative from fp rounding at branch pt
    float ey1 = fmaf(E_F, y, 1.0f);
    float p2 = fmaxf(ey1 + ey1, 0.0f);
    float p = __builtin_amdgcn_sqrtf(p2);
    // Pade[2/2] for (w+1)/p
    float num = fmaf(p, fmaf(p, 0.018055f, 0.5f), 1.0f);
    float den = fmaf(p, fmaf(p, 0.143051f, 0.833323f), 1.0f);
    float wp1 = p * num * fast_rcp(den);     // w0 + 1 >= 0
    float w = wp1 - 1.0f;
    // One Newton step: w -= (w e^w - y) / (e^w (w+1))
    // Guard +1e-4: near branch f is rounding noise (~3e-8) while den2 -> 0;
    // 1e-4 caps the spurious step at ~3e-4 where dout/dw = 0.2*(w+1) ~ 0.
    float ew = __expf(w);
    float f = fmaf(w, ew, -y);
    float den2 = fmaf(ew, wp1, 1e-4f);
    w = fmaf(-f, fast_rcp(den2), w);
    float out_u = 0.1f * (w * (w + 2.0f));   // w/5 + 0.1 w^2
    float out_c = fmaf(E_F, d, 0.1f);        // clamped: sigma = e, w = -1
    return (t5 < NEG_INV_E) ? out_c : out_u;
}

__global__ void reduce_partial(const float4* __restrict__ x, float* __restrict__ partials,
                               int n4, const float* __restrict__ x_scalar, int n) {
    float s = 0.0f;
    int stride = gridDim.x * blockDim.x;
    for (int i = blockIdx.x * blockDim.x + threadIdx.x; i < n4; i += stride) {
        float4 v = x[i];
        s += (v.x + v.y) + (v.z + v.w);
    }
    if (blockIdx.x == 0 && threadIdx.x == 0) {
        for (int i = 4 * n4; i < n; ++i) s += x_scalar[i];
    }
#pragma unroll
    for (int off = 32; off > 0; off >>= 1) s += __shfl_down(s, off, 64);
    __shared__ float smem[4];
    int lane = threadIdx.x & 63;
    int wave = threadIdx.x >> 6;
    if (lane == 0) smem[wave] = s;
    __syncthreads();
    if (threadIdx.x == 0) {
        partials[blockIdx.x] = (smem[0] + smem[1]) + (smem[2] + smem[3]);
    }
}

__global__ void finalize_tau(const float* __restrict__ partials, float* __restrict__ tau_p, int n) {
    double s = 0.0;
    for (int i = threadIdx.x; i < NPART; i += 256) s += (double)partials[i];
#pragma unroll
    for (int off = 32; off > 0; off >>= 1) s += __shfl_down(s, off, 64);
    __shared__ double smem[4];
    int lane = threadIdx.x & 63;
    int wave = threadIdx.x >> 6;
    if (lane == 0) smem[wave] = s;
    __syncthreads();
    if (threadIdx.x == 0) {
        double total = (smem[0] + smem[1]) + (smem[2] + smem[3]);
        tau_p[0] = (float)(total / (double)n);
    }
}

__global__ void superloss_main(const float4* __restrict__ x, float4* __restrict__ out,
                               const float* __restrict__ tau_p, int n4) {
    int i = blockIdx.x * blockDim.x + threadIdx.x;
    if (i >= n4) return;
    float tau = *tau_p;
    float4 v = x[i];
    float4 r;
    r.x = superloss_elem(v.x, tau);
    r.y = superloss_elem(v.y, tau);
    r.z = superloss_elem(v.z, tau);
    r.w = superloss_elem(v.w, tau);
    out[i] = r;
}

__global__ void superloss_tail(const float* __restrict__ x, float* __restrict__ out,
                               const float* __restrict__ tau_p, int start, int n) {
    int i = start + blockIdx.x * blockDim.x + threadIdx.x;
    if (i < n) out[i] = superloss_elem(x[i], *tau_p);
}

extern "C" void kernel_launch(void* const* d_in, const int* in_sizes, int n_in,
                              void* d_out, int out_size, void* d_ws, size_t ws_size,
                              hipStream_t stream) {
    const float* loss = (const float*)d_in[0];
    float* out = (float*)d_out;
    int n = in_sizes[0];
    int n4 = n / 4;
    float* ws = (float*)d_ws;          // ws[0..NPART-1] partials, ws[NPART] = tau
    float* tau_p = ws + NPART;

    reduce_partial<<<NPART, 256, 0, stream>>>((const float4*)loss, ws, n4, loss, n);
    finalize_tau<<<1, 256, 0, stream>>>(ws, tau_p, n);

    int blocks = (n4 + 255) / 256;
    superloss_main<<<blocks, 256, 0, stream>>>((const float4*)loss, (float4*)out, tau_p, n4);

    int tail = n - 4 * n4;
    if (tail > 0) {
        superloss_tail<<<(tail + 255) / 256, 256, 0, stream>>>(loss, out, tau_p, 4 * n4, n);
    }
}